// Round 5
// baseline (134.683 us; speedup 1.0000x reference)
//
#include <hip/hip_runtime.h>

// HeightmapNormalsLoss: fused Sobel-normals + L1 mean over two [32,1,512,512] fp32 images.
// R5: occupancy push. 8 waves/block (2 col-halves x 4 row-subbands), RPW=4,
// __launch_bounds__(512,6) -> VGPR<=85, 24 waves/CU resident (was 16).
// Same register-rolling separable math as R3/R4 (absmax 0.0).

#define IMG_H 512
#define IMG_W 512
#define RPW   4              // output rows per wave
#define BAND  (4 * RPW)      // 16 rows per block (4 row-subbands)
#define NT    512            // 8 waves: 2 column halves x 4 row subbands

// Horizontal prefilters for one row: u = [1,0,-1] cross-corr, v = [1,2,1].
__device__ __forceinline__ void hfilt(float4 x, float xh, int lane, int colHalf,
                                      float4& u, float4& v) {
    float xm = __shfl_up(x.w, 1, 64);    // left neighbor of this lane's col0
    float xp = __shfl_down(x.x, 1, 64);  // right neighbor of this lane's col3
    if (lane == 0)  xm = (colHalf == 0) ? x.x : xh;   // image edge clamp / cross-wave halo
    if (lane == 63) xp = (colHalf == 1) ? x.w : xh;
    u.x = xm  - x.y;  u.y = x.x - x.z;  u.z = x.y - x.w;  u.w = x.z - xp;
    v.x = xm  + 2.f * x.x + x.y;
    v.y = x.x + 2.f * x.y + x.z;
    v.z = x.y + 2.f * x.z + x.w;
    v.w = x.z + 2.f * x.w + xp;
}

// |n(gen) - n(tgt)| summed over 3 components for one pixel.
// n = (4gx, 4gy, sqrt(1-q)) * rsqrt(63q+1), q = gx^2+gy^2  (algebraic fold, absmax 0.0 in R3/R4).
__device__ __forceinline__ float pixdiff(float gxa, float gya, float gxb, float gyb) {
    float qa = fmaf(gxa, gxa, gya * gya);
    float qb = fmaf(gxb, gxb, gyb * gyb);
    float ta = rsqrtf(fmaf(63.f, qa, 1.f));
    float tb = rsqrtf(fmaf(63.f, qb, 1.f));
    return fabsf(4.f * gxa * ta - 4.f * gxb * tb)
         + fabsf(4.f * gya * ta - 4.f * gyb * tb)
         + fabsf(sqrtf(1.f - qa) * ta - sqrtf(1.f - qb) * tb);
}

__global__ __launch_bounds__(NT, 6)
void hnl_main(const float* __restrict__ gen, const float* __restrict__ tgt,
              float* __restrict__ partial) {
    const int t    = threadIdx.x;
    const int wave = t >> 6;
    const int lane = t & 63;
    const int colHalf = wave & 1;        // 0: cols 0..255, 1: cols 256..511
    const int rowSub  = wave >> 1;       // 0..3
    const int rbase = blockIdx.x * BAND + rowSub * RPW;
    const int c0 = colHalf * 256 + lane * 4;

    const size_t ib = (size_t)blockIdx.y * (IMG_H * IMG_W);
    const float* gp = gen + ib;
    const float* tp = tgt + ib;

    const bool haloL = (lane == 0)  && (colHalf == 1);   // needs col 255
    const bool haloR = (lane == 63) && (colHalf == 0);   // needs col 256
    const bool needHalo = haloL || haloR;
    const int  haloCol = haloL ? 255 : 256;

    auto rowptr = [&](const float* base, int r) {
        int rc = min(IMG_H - 1, max(0, r));              // ReplicationPad2d vertical clamp
        return base + (size_t)rc * IMG_W;
    };
    auto ld = [&](const float* rp, float4& x, float& xh) {
        x  = *reinterpret_cast<const float4*>(rp + c0);
        xh = needHalo ? rp[haloCol] : 0.f;
    };

    // ---- prologue: rows rbase-1 .. rbase+2 ----
    float4 x0g, x0t, x1g, x1t;
    float  h0g, h0t, h1g, h1t;
    ld(rowptr(gp, rbase - 1), x0g, h0g); ld(rowptr(tp, rbase - 1), x0t, h0t);
    ld(rowptr(gp, rbase    ), x1g, h1g); ld(rowptr(tp, rbase    ), x1t, h1t);

    float4 rg, rt;  float rhg, rht;                      // raw row (i+1), ready
    ld(rowptr(gp, rbase + 1), rg, rhg); ld(rowptr(tp, rbase + 1), rt, rht);
    float4 fg, ft;  float fhg, fht;                      // raw row (i+2), in flight
    ld(rowptr(gp, rbase + 2), fg, fhg); ld(rowptr(tp, rbase + 2), ft, fht);

    float4 gup, gvp, guc, gvc, tup, tvp, tuc, tvc;
    hfilt(x0g, h0g, lane, colHalf, gup, gvp); hfilt(x0t, h0t, lane, colHalf, tup, tvp);
    hfilt(x1g, h1g, lane, colHalf, guc, gvc); hfilt(x1t, h1t, lane, colHalf, tuc, tvc);

    float acc = 0.f;
    #pragma unroll
    for (int i = 0; i < RPW; ++i) {
        // issue loads for row rbase+i+3 (consumed at iter i+2)
        float4 ng = fg, nt_ = ft;  float nhg = fhg, nht = fht;
        if (i < RPW - 2) {
            ld(rowptr(gp, rbase + i + 3), ng, nhg);
            ld(rowptr(tp, rbase + i + 3), nt_, nht);
        }

        // filter the ready raw row (rbase+i+1)
        float4 gun, gvn, tun, tvn;
        hfilt(rg, rhg, lane, colHalf, gun, gvn);
        hfilt(rt, rht, lane, colHalf, tun, tvn);

        acc += pixdiff(gup.x + 2.f * guc.x + gun.x, gvp.x - gvn.x,
                       tup.x + 2.f * tuc.x + tun.x, tvp.x - tvn.x);
        acc += pixdiff(gup.y + 2.f * guc.y + gun.y, gvp.y - gvn.y,
                       tup.y + 2.f * tuc.y + tun.y, tvp.y - tvn.y);
        acc += pixdiff(gup.z + 2.f * guc.z + gun.z, gvp.z - gvn.z,
                       tup.z + 2.f * tuc.z + tun.z, tvp.z - tvn.z);
        acc += pixdiff(gup.w + 2.f * guc.w + gun.w, gvp.w - gvn.w,
                       tup.w + 2.f * tuc.w + tun.w, tvp.w - tvn.w);

        gup = guc; guc = gun; gvp = gvc; gvc = gvn;
        tup = tuc; tuc = tun; tvp = tvc; tvc = tvn;
        rg = fg; rhg = fhg; rt = ft; rht = fht;
        fg = ng; fhg = nhg; ft = nt_; fht = nht;
    }

    // wave butterfly + block reduce, one partial per block (no global atomics)
    #pragma unroll
    for (int o = 32; o; o >>= 1) acc += __shfl_xor(acc, o, 64);
    __shared__ float wsum[NT / 64];
    if (lane == 0) wsum[wave] = acc;
    __syncthreads();
    if (t == 0) {
        float s = 0.f;
        #pragma unroll
        for (int w = 0; w < NT / 64; ++w) s += wsum[w];
        partial[blockIdx.y * gridDim.x + blockIdx.x] = s;
    }
}

__global__ __launch_bounds__(256)
void hnl_reduce(const float* __restrict__ partial, float* __restrict__ out,
                int n, float scale) {
    const int t = threadIdx.x;
    float s = 0.f;
    for (int i = t; i < n; i += 256) s += partial[i];
    #pragma unroll
    for (int o = 32; o; o >>= 1) s += __shfl_xor(s, o, 64);
    __shared__ float wsum[4];
    if ((t & 63) == 0) wsum[t >> 6] = s;
    __syncthreads();
    if (t == 0) out[0] = (wsum[0] + wsum[1] + wsum[2] + wsum[3]) * scale;
}

extern "C" void kernel_launch(void* const* d_in, const int* in_sizes, int n_in,
                              void* d_out, int out_size, void* d_ws, size_t ws_size,
                              hipStream_t stream) {
    const float* gen = (const float*)d_in[0];
    const float* tgt = (const float*)d_in[1];
    float* out = (float*)d_out;
    float* ws  = (float*)d_ws;

    const int B = in_sizes[0] / (IMG_H * IMG_W);     // 32
    const int nBands = IMG_H / BAND;                 // 32
    const int nPartials = B * nBands;                // 1024
    const float scale = 1.f / ((float)B * 3.f * IMG_H * IMG_W);

    dim3 grid(nBands, B);                            // (32, 32) = 1024 blocks x 8 waves
    hnl_main<<<grid, NT, 0, stream>>>(gen, tgt, ws);
    hnl_reduce<<<1, 256, 0, stream>>>(ws, out, nPartials, scale);
}

// Round 6
// 105.945 us; speedup vs baseline: 1.2713x; 1.2713x over previous
//
#include <hip/hip_runtime.h>

// HeightmapNormalsLoss: fused Sobel-normals + L1 mean over two [32,1,512,512] fp32 images.
// R6: R4's spill-free register structure (NT=256, no min-wave cap, 2-deep pipeline),
// occupancy raised via grid: BAND=8/RPW=4 -> 2048 blocks x 4 waves = 32 waves/CU supplied.

#define IMG_H 512
#define IMG_W 512
#define RPW   4              // output rows per wave
#define BAND  (2 * RPW)      // 8 rows per block (2 row-subbands)
#define NT    256            // 4 waves: 2 column halves x 2 row subbands

// Horizontal prefilters for one row: u = [1,0,-1] cross-corr, v = [1,2,1].
__device__ __forceinline__ void hfilt(float4 x, float xh, int lane, int colHalf,
                                      float4& u, float4& v) {
    float xm = __shfl_up(x.w, 1, 64);    // left neighbor of this lane's col0
    float xp = __shfl_down(x.x, 1, 64);  // right neighbor of this lane's col3
    if (lane == 0)  xm = (colHalf == 0) ? x.x : xh;   // image edge clamp / cross-wave halo
    if (lane == 63) xp = (colHalf == 1) ? x.w : xh;
    u.x = xm  - x.y;  u.y = x.x - x.z;  u.z = x.y - x.w;  u.w = x.z - xp;
    v.x = xm  + 2.f * x.x + x.y;
    v.y = x.x + 2.f * x.y + x.z;
    v.z = x.y + 2.f * x.z + x.w;
    v.w = x.z + 2.f * x.w + xp;
}

// |n(gen) - n(tgt)| summed over 3 components for one pixel.
// n = (4gx, 4gy, sqrt(1-q)) * rsqrt(63q+1), q = gx^2+gy^2  (algebraic fold, absmax 0.0 in R3/R4).
__device__ __forceinline__ float pixdiff(float gxa, float gya, float gxb, float gyb) {
    float qa = fmaf(gxa, gxa, gya * gya);
    float qb = fmaf(gxb, gxb, gyb * gyb);
    float ta = rsqrtf(fmaf(63.f, qa, 1.f));
    float tb = rsqrtf(fmaf(63.f, qb, 1.f));
    return fabsf(4.f * gxa * ta - 4.f * gxb * tb)
         + fabsf(4.f * gya * ta - 4.f * gyb * tb)
         + fabsf(sqrtf(1.f - qa) * ta - sqrtf(1.f - qb) * tb);
}

__global__ __launch_bounds__(NT)
void hnl_main(const float* __restrict__ gen, const float* __restrict__ tgt,
              float* __restrict__ partial) {
    const int t    = threadIdx.x;
    const int wave = t >> 6;
    const int lane = t & 63;
    const int colHalf = wave & 1;        // 0: cols 0..255, 1: cols 256..511
    const int rowSub  = wave >> 1;       // 0..1
    const int rbase = blockIdx.x * BAND + rowSub * RPW;
    const int c0 = colHalf * 256 + lane * 4;

    const size_t ib = (size_t)blockIdx.y * (IMG_H * IMG_W);
    const float* gp = gen + ib;
    const float* tp = tgt + ib;

    const bool haloL = (lane == 0)  && (colHalf == 1);   // needs col 255
    const bool haloR = (lane == 63) && (colHalf == 0);   // needs col 256
    const bool needHalo = haloL || haloR;
    const int  haloCol = haloL ? 255 : 256;

    auto rowptr = [&](const float* base, int r) {
        int rc = min(IMG_H - 1, max(0, r));              // ReplicationPad2d vertical clamp
        return base + (size_t)rc * IMG_W;
    };
    auto ld = [&](const float* rp, float4& x, float& xh) {
        x  = *reinterpret_cast<const float4*>(rp + c0);
        xh = needHalo ? rp[haloCol] : 0.f;
    };

    // ---- prologue: rows rbase-1 .. rbase+2 ----
    float4 x0g, x0t, x1g, x1t;
    float  h0g, h0t, h1g, h1t;
    ld(rowptr(gp, rbase - 1), x0g, h0g); ld(rowptr(tp, rbase - 1), x0t, h0t);
    ld(rowptr(gp, rbase    ), x1g, h1g); ld(rowptr(tp, rbase    ), x1t, h1t);

    float4 rg, rt;  float rhg, rht;                      // raw row (i+1), ready
    ld(rowptr(gp, rbase + 1), rg, rhg); ld(rowptr(tp, rbase + 1), rt, rht);
    float4 fg, ft;  float fhg, fht;                      // raw row (i+2), in flight
    ld(rowptr(gp, rbase + 2), fg, fhg); ld(rowptr(tp, rbase + 2), ft, fht);

    float4 gup, gvp, guc, gvc, tup, tvp, tuc, tvc;
    hfilt(x0g, h0g, lane, colHalf, gup, gvp); hfilt(x0t, h0t, lane, colHalf, tup, tvp);
    hfilt(x1g, h1g, lane, colHalf, guc, gvc); hfilt(x1t, h1t, lane, colHalf, tuc, tvc);

    float acc = 0.f;
    #pragma unroll
    for (int i = 0; i < RPW; ++i) {
        // issue loads for row rbase+i+3 (consumed at iter i+2)
        float4 ng = fg, nt_ = ft;  float nhg = fhg, nht = fht;
        if (i < RPW - 2) {
            ld(rowptr(gp, rbase + i + 3), ng, nhg);
            ld(rowptr(tp, rbase + i + 3), nt_, nht);
        }

        // filter the ready raw row (rbase+i+1)
        float4 gun, gvn, tun, tvn;
        hfilt(rg, rhg, lane, colHalf, gun, gvn);
        hfilt(rt, rht, lane, colHalf, tun, tvn);

        acc += pixdiff(gup.x + 2.f * guc.x + gun.x, gvp.x - gvn.x,
                       tup.x + 2.f * tuc.x + tun.x, tvp.x - tvn.x);
        acc += pixdiff(gup.y + 2.f * guc.y + gun.y, gvp.y - gvn.y,
                       tup.y + 2.f * tuc.y + tun.y, tvp.y - tvn.y);
        acc += pixdiff(gup.z + 2.f * guc.z + gun.z, gvp.z - gvn.z,
                       tup.z + 2.f * tuc.z + tun.z, tvp.z - tvn.z);
        acc += pixdiff(gup.w + 2.f * guc.w + gun.w, gvp.w - gvn.w,
                       tup.w + 2.f * tuc.w + tun.w, tvp.w - tvn.w);

        gup = guc; guc = gun; gvp = gvc; gvc = gvn;
        tup = tuc; tuc = tun; tvp = tvc; tvc = tvn;
        rg = fg; rhg = fhg; rt = ft; rht = fht;
        fg = ng; fhg = nhg; ft = nt_; fht = nht;
    }

    // wave butterfly + block reduce, one partial per block (no global atomics)
    #pragma unroll
    for (int o = 32; o; o >>= 1) acc += __shfl_xor(acc, o, 64);
    __shared__ float wsum[NT / 64];
    if (lane == 0) wsum[wave] = acc;
    __syncthreads();
    if (t == 0) {
        float s = 0.f;
        #pragma unroll
        for (int w = 0; w < NT / 64; ++w) s += wsum[w];
        partial[blockIdx.y * gridDim.x + blockIdx.x] = s;
    }
}

__global__ __launch_bounds__(256)
void hnl_reduce(const float* __restrict__ partial, float* __restrict__ out,
                int n, float scale) {
    const int t = threadIdx.x;
    float s = 0.f;
    for (int i = t; i < n; i += 256) s += partial[i];
    #pragma unroll
    for (int o = 32; o; o >>= 1) s += __shfl_xor(s, o, 64);
    __shared__ float wsum[4];
    if ((t & 63) == 0) wsum[t >> 6] = s;
    __syncthreads();
    if (t == 0) out[0] = (wsum[0] + wsum[1] + wsum[2] + wsum[3]) * scale;
}

extern "C" void kernel_launch(void* const* d_in, const int* in_sizes, int n_in,
                              void* d_out, int out_size, void* d_ws, size_t ws_size,
                              hipStream_t stream) {
    const float* gen = (const float*)d_in[0];
    const float* tgt = (const float*)d_in[1];
    float* out = (float*)d_out;
    float* ws  = (float*)d_ws;

    const int B = in_sizes[0] / (IMG_H * IMG_W);     // 32
    const int nBands = IMG_H / BAND;                 // 64
    const int nPartials = B * nBands;                // 2048
    const float scale = 1.f / ((float)B * 3.f * IMG_H * IMG_W);

    dim3 grid(nBands, B);                            // (64, 32) = 2048 blocks x 4 waves
    hnl_main<<<grid, NT, 0, stream>>>(gen, tgt, ws);
    hnl_reduce<<<1, 256, 0, stream>>>(ws, out, nPartials, scale);
}